// Round 2
// baseline (854.573 us; speedup 1.0000x reference)
//
#include <hip/hip_runtime.h>
#include <hip/hip_bf16.h>
#include <math.h>

#define D 64
#define K 1024
#define N_VEC 262144  // 64*64*64
#define EPS_DIST 1e-2f
#define FLAG_CAP 65536

typedef __attribute__((ext_vector_type(8))) short short8v;   // 8 bf16 (4 VGPRs)
typedef __attribute__((ext_vector_type(4))) float f32x4;

__device__ __forceinline__ unsigned short f2bf_rne(float f) {
  unsigned u = __builtin_bit_cast(unsigned, f);
  u += 0x7FFFu + ((u >> 16) & 1u);
  return (unsigned short)(u >> 16);
}
__device__ __forceinline__ float bf2f(unsigned short h) {
  unsigned u = ((unsigned)h) << 16;
  return __builtin_bit_cast(float, u);
}

// ---------------------------------------------------------------------------
// ws layout (4-byte units):
//   [0, K)                 : counts (uint)
//   [K]                    : sq accum (float)
//   [K+1]                  : flag counter (uint)
//   [K+2, K+4)             : pad
//   [K+4, 2K+4)            : cnorm (float)
//   [2K+4, 3K+4)           : hcn = -0.5*cnorm (float)
//   [3K+4, 3K+4+FLAG_CAP)  : flag list (uint)
//   then: packed split codebook, K rows x 128 bf16 (hi[64] | lo[64]) = 256 KB
// ---------------------------------------------------------------------------

__global__ __launch_bounds__(256) void vq_prep_kernel(
    const float* __restrict__ cb, float* __restrict__ cnorm,
    float* __restrict__ hcn, unsigned short* __restrict__ pk) {
  int k = blockIdx.x * 256 + threadIdx.x;
  if (k >= K) return;
  const float* c = cb + (size_t)k * D;
  unsigned short* row = pk + (size_t)k * 128;
  float s = 0.f;
#pragma unroll
  for (int j = 0; j < D; ++j) {
    float f = c[j];
    s = fmaf(f, f, s);
    unsigned short h = f2bf_rne(f);
    float lo = f - bf2f(h);
    row[j] = h;
    row[64 + j] = f2bf_rne(lo);
  }
  cnorm[k] = s;
  hcn[k] = -0.5f * s;
}

// Each block: 256 rows. Each wave: 64 rows (4 row-tiles of 16).
// T = x.c - 0.5*|c|^2 ; dist = -2T + |x|^2  =>  argmin dist == argmax T.
__global__ __launch_bounds__(256) void vq_argmin_mfma_kernel(
    const float* __restrict__ x, const unsigned short* __restrict__ pk,
    const float* __restrict__ hcn, float* __restrict__ tok_out,
    unsigned int* __restrict__ counts, unsigned int* __restrict__ flag_cnt,
    unsigned int* __restrict__ flag_list) {
  __shared__ unsigned int hist[K];
  for (int i = threadIdx.x; i < K; i += 256) hist[i] = 0u;
  __syncthreads();

  const int lane = threadIdx.x & 63;
  const int w = threadIdx.x >> 6;
  const int c16 = lane & 15;  // A row within tile / B col within tile
  const int g4 = lane >> 4;   // k-group
  const int wave_base = blockIdx.x * 256 + w * 64;

  // A fragments: 4 row-tiles x 2 k-steps x (hi, lo), held for whole K loop
  short8v ah[4][2], al[4][2];
#pragma unroll
  for (int rt = 0; rt < 4; ++rt) {
#pragma unroll
    for (int s = 0; s < 2; ++s) {
      int row = wave_base + rt * 16 + c16;
      const float* p = x + (size_t)row * D + s * 32 + g4 * 8;
      float4 f0 = *(const float4*)(p);
      float4 f1 = *(const float4*)(p + 4);
      float ff[8] = {f0.x, f0.y, f0.z, f0.w, f1.x, f1.y, f1.z, f1.w};
      short8v h, l;
#pragma unroll
      for (int j = 0; j < 8; ++j) {
        unsigned short hb = f2bf_rne(ff[j]);
        float lo = ff[j] - bf2f(hb);
        h[j] = (short)hb;
        l[j] = (short)f2bf_rne(lo);
      }
      ah[rt][s] = h;
      al[rt][s] = l;
    }
  }

  float bT[4][4], b2T[4][4];
  int bidx[4][4];
#pragma unroll
  for (int rt = 0; rt < 4; ++rt)
#pragma unroll
    for (int r = 0; r < 4; ++r) {
      bT[rt][r] = -3.4e38f;
      b2T[rt][r] = -3.4e38f;
      bidx[rt][r] = 0;
    }

  const unsigned short* pbase = pk + (size_t)c16 * 128 + (size_t)g4 * 8;
  const float* hcnp = hcn + c16;

  for (int t = 0; t < K / 16; ++t) {
    short8v bh0 = *(const short8v*)(pbase);        // hi, k-step 0
    short8v bh1 = *(const short8v*)(pbase + 32);   // hi, k-step 1
    short8v bl0 = *(const short8v*)(pbase + 64);   // lo, k-step 0
    short8v bl1 = *(const short8v*)(pbase + 96);   // lo, k-step 1
    float hc = *hcnp;                              // -0.5*|c|^2 for this lane's col
    f32x4 cinit = {hc, hc, hc, hc};
    const int code = t * 16 + c16;
#pragma unroll
    for (int rt = 0; rt < 4; ++rt) {
      f32x4 acc = cinit;
      acc = __builtin_amdgcn_mfma_f32_16x16x32_bf16(ah[rt][0], bh0, acc, 0, 0, 0);
      acc = __builtin_amdgcn_mfma_f32_16x16x32_bf16(ah[rt][1], bh1, acc, 0, 0, 0);
      acc = __builtin_amdgcn_mfma_f32_16x16x32_bf16(ah[rt][0], bl0, acc, 0, 0, 0);
      acc = __builtin_amdgcn_mfma_f32_16x16x32_bf16(ah[rt][1], bl1, acc, 0, 0, 0);
      acc = __builtin_amdgcn_mfma_f32_16x16x32_bf16(al[rt][0], bh0, acc, 0, 0, 0);
      acc = __builtin_amdgcn_mfma_f32_16x16x32_bf16(al[rt][1], bh1, acc, 0, 0, 0);
#pragma unroll
      for (int r = 0; r < 4; ++r) {
        float T = acc[r];
        // second-max = max(old b2, min(old b, T))  (valid since b >= b2)
        b2T[rt][r] = fmaxf(b2T[rt][r], fminf(bT[rt][r], T));
        bool gt = T > bT[rt][r];  // strict > keeps earliest (lowest) code on tie
        bT[rt][r] = fmaxf(bT[rt][r], T);
        bidx[rt][r] = gt ? code : bidx[rt][r];
      }
    }
    pbase += 16 * 128;
    hcnp += 16;
  }

  // reduce across the 16 lanes (cols) of each lane-group; max T, lower idx on tie
#pragma unroll
  for (int rt = 0; rt < 4; ++rt) {
#pragma unroll
    for (int r = 0; r < 4; ++r) {
      float b = bT[rt][r], b2 = b2T[rt][r];
      int idx = bidx[rt][r];
#pragma unroll
      for (int m = 1; m < 16; m <<= 1) {
        float ob = __shfl_xor(b, m, 64);
        float ob2 = __shfl_xor(b2, m, 64);
        int oi = __shfl_xor(idx, m, 64);
        float nb2 = fmaxf(fmaxf(b2, ob2), fminf(b, ob));
        bool take = (ob > b) || (ob == b && oi < idx);
        b = take ? ob : b;
        idx = take ? oi : idx;
        b2 = nb2;
      }
      if (c16 == 0) {
        int grow = wave_base + rt * 16 + g4 * 4 + r;
        tok_out[grow] = (float)idx;
        atomicAdd(&hist[idx], 1u);
        // dist gap = 2*(b - b2); flag near-ties for exact fp32 recheck
        if (b - b2 < 0.5f * EPS_DIST) {
          unsigned p = atomicAdd(flag_cnt, 1u);
          if (p < FLAG_CAP) flag_list[p] = (unsigned)grow;
        }
      }
    }
  }
  __syncthreads();
  for (int i = threadIdx.x; i < K; i += 256) {
    unsigned h = hist[i];
    if (h) atomicAdd(&counts[i], h);
  }
}

// One wave per flagged vector: exact fp32 rescan, bit-identical formula to the
// round-1 kernel (which matched the numpy reference exactly).
__global__ __launch_bounds__(256) void vq_cleanup_kernel(
    const float* __restrict__ x, const float* __restrict__ cb,
    const float* __restrict__ cnorm, float* __restrict__ tok,
    unsigned int* __restrict__ counts, const unsigned int* __restrict__ flag_cnt,
    const unsigned int* __restrict__ flag_list) {
  const int lane = threadIdx.x & 63;
  const int gw = blockIdx.x * (blockDim.x >> 6) + (threadIdx.x >> 6);
  const int nw = gridDim.x * (blockDim.x >> 6);
  unsigned nf = *flag_cnt;
  if (nf > FLAG_CAP) nf = FLAG_CAP;
  for (unsigned f = gw; f < nf; f += nw) {
    int vid = (int)flag_list[f];
    const float* xv = x + (size_t)vid * D;
    float xr[D];
#pragma unroll
    for (int j = 0; j < 16; ++j) {
      float4 v = ((const float4*)xv)[j];
      xr[4 * j] = v.x; xr[4 * j + 1] = v.y;
      xr[4 * j + 2] = v.z; xr[4 * j + 3] = v.w;
    }
    float xx = 0.f;
#pragma unroll
    for (int j = 0; j < D; ++j) xx = fmaf(xr[j], xr[j], xx);
    float best = 3.4e38f;
    int bidx = K;
    for (int i = 0; i < 16; ++i) {
      int k = lane * 16 + i;
      const float* c = cb + (size_t)k * D;
      float acc = 0.f;
#pragma unroll
      for (int j = 0; j < D; ++j) acc = fmaf(xr[j], c[j], acc);
      float dist = (xx + cnorm[k]) - 2.0f * acc;
      if (dist < best) { best = dist; bidx = k; }
    }
#pragma unroll
    for (int m = 1; m < 64; m <<= 1) {
      float ob = __shfl_xor(best, m, 64);
      int oi = __shfl_xor(bidx, m, 64);
      bool take = (ob < best) || (ob == best && oi < bidx);
      best = take ? ob : best;
      bidx = take ? oi : bidx;
    }
    if (lane == 0) {
      int old = (int)tok[vid];
      if (old != bidx) {
        tok[vid] = (float)bidx;
        atomicAdd(&counts[old], 0xFFFFFFFFu);  // -1
        atomicAdd(&counts[bidx], 1u);
      }
    }
  }
}

__device__ __forceinline__ float block_reduce_sum_256(float v) {
#pragma unroll
  for (int o = 32; o > 0; o >>= 1) v += __shfl_down(v, o, 64);
  __shared__ float s[4];
  int lane = threadIdx.x & 63;
  int w = threadIdx.x >> 6;
  if (lane == 0) s[w] = v;
  __syncthreads();
  float r = 0.f;
  if (threadIdx.x == 0) r = s[0] + s[1] + s[2] + s[3];
  return r;  // valid on thread 0 only
}

__global__ __launch_bounds__(256) void vq_gather_kernel(
    const float* __restrict__ x, const float* __restrict__ cb,
    const float* __restrict__ tok, float* __restrict__ outq,
    float* __restrict__ sq_accum) {
  const int total4 = N_VEC * (D / 4);
  float sq = 0.f;
  for (int idx4 = blockIdx.x * 256 + threadIdx.x; idx4 < total4;
       idx4 += gridDim.x * 256) {
    int vid = idx4 >> 4;
    int j4 = idx4 & 15;
    int t = (int)tok[vid];
    float4 xv = reinterpret_cast<const float4*>(x)[idx4];
    float4 cv = reinterpret_cast<const float4*>(cb + (size_t)t * D)[j4];
    float dx0 = cv.x - xv.x, dx1 = cv.y - xv.y;
    float dx2 = cv.z - xv.z, dx3 = cv.w - xv.w;
    float4 q;
    q.x = xv.x + dx0; q.y = xv.y + dx1;
    q.z = xv.z + dx2; q.w = xv.w + dx3;
    reinterpret_cast<float4*>(outq)[idx4] = q;
    sq = fmaf(dx0, dx0, sq);
    sq = fmaf(dx1, dx1, sq);
    sq = fmaf(dx2, dx2, sq);
    sq = fmaf(dx3, dx3, sq);
  }
  float bs = block_reduce_sum_256(sq);
  if (threadIdx.x == 0) atomicAdd(sq_accum, bs);
}

__global__ __launch_bounds__(256) void vq_finalize_kernel(
    const unsigned int* __restrict__ counts, const float* __restrict__ sq_accum,
    float* __restrict__ out_scalars) {
  float h = 0.f;
  for (int i = threadIdx.x; i < K; i += 256) {
    float p = (float)counts[i] / (float)N_VEC;
    h -= p * logf(p + 1e-10f);
  }
  float hs = block_reduce_sum_256(h);
  if (threadIdx.x == 0) {
    float m = sq_accum[0] / (float)((size_t)N_VEC * D);
    out_scalars[0] = 1.25f * m;  // vq_loss
    out_scalars[1] = 0.25f * m;  // commitment_loss
    out_scalars[2] = m;          // codebook_loss
    out_scalars[3] = expf(hs);   // perplexity
  }
}

extern "C" void kernel_launch(void* const* d_in, const int* in_sizes, int n_in,
                              void* d_out, int out_size, void* d_ws,
                              size_t ws_size, hipStream_t stream) {
  const float* x = (const float*)d_in[0];
  const float* cb = (const float*)d_in[1];

  float* outq = (float*)d_out;
  float* tok = outq + (size_t)N_VEC * D;
  float* scal = tok + N_VEC;

  unsigned int* counts = (unsigned int*)d_ws;                 // K
  float* sq = (float*)d_ws + K;                               // 1
  unsigned int* flag_cnt = (unsigned int*)d_ws + K + 1;       // 1
  float* cnorm = (float*)d_ws + K + 4;                        // K
  float* hcn = (float*)d_ws + 2 * K + 4;                      // K
  unsigned int* flag_list = (unsigned int*)d_ws + 3 * K + 4;  // FLAG_CAP
  unsigned short* pk =
      (unsigned short*)((unsigned int*)d_ws + 3 * K + 4 + FLAG_CAP);

  // zero counts + sq + flag counter every call
  hipMemsetAsync(d_ws, 0, (size_t)(K + 2) * sizeof(float), stream);

  vq_prep_kernel<<<(K + 255) / 256, 256, 0, stream>>>(cb, cnorm, hcn, pk);
  vq_argmin_mfma_kernel<<<N_VEC / 256, 256, 0, stream>>>(
      x, pk, hcn, tok, counts, flag_cnt, flag_list);
  vq_cleanup_kernel<<<64, 256, 0, stream>>>(x, cb, cnorm, tok, counts,
                                            flag_cnt, flag_list);
  vq_gather_kernel<<<4096, 256, 0, stream>>>(x, cb, tok, outq, sq);
  vq_finalize_kernel<<<1, 256, 0, stream>>>(counts, sq, scal);
}

// Round 3
// 451.123 us; speedup vs baseline: 1.8943x; 1.8943x over previous
//
#include <hip/hip_runtime.h>
#include <hip/hip_bf16.h>
#include <math.h>

#define D 64
#define K 1024
#define N_VEC 262144  // 64*64*64
#define EPS_DIST 1e-2f
#define FLAG_CAP 65536

typedef __attribute__((ext_vector_type(8))) short short8v;   // 8 bf16 (4 VGPRs)
typedef __attribute__((ext_vector_type(4))) float f32x4;

__device__ __forceinline__ unsigned short f2bf_rne(float f) {
  unsigned u = __builtin_bit_cast(unsigned, f);
  u += 0x7FFFu + ((u >> 16) & 1u);
  return (unsigned short)(u >> 16);
}
__device__ __forceinline__ float bf2f(unsigned short h) {
  unsigned u = ((unsigned)h) << 16;
  return __builtin_bit_cast(float, u);
}

// ---------------------------------------------------------------------------
// ws layout (4-byte units):
//   [0, K)                 : counts (uint)
//   [K]                    : sq accum (float)
//   [K+1]                  : flag counter (uint)
//   [K+2, K+4)             : pad
//   [K+4, 2K+4)            : cnorm (float)
//   [2K+4, 3K+4)           : hcn = -0.5*cnorm (float)
//   [3K+4, 3K+4+FLAG_CAP)  : flag list (uint)
//   then: packed split codebook, K rows x 128 bf16 (hi[64] | lo[64]) = 256 KB
// ---------------------------------------------------------------------------

__global__ __launch_bounds__(256) void vq_prep_kernel(
    const float* __restrict__ cb, float* __restrict__ cnorm,
    float* __restrict__ hcn, unsigned short* __restrict__ pk) {
  int k = blockIdx.x * 256 + threadIdx.x;
  if (k >= K) return;
  const float* c = cb + (size_t)k * D;
  unsigned short* row = pk + (size_t)k * 128;
  float s = 0.f;
#pragma unroll
  for (int j = 0; j < D; ++j) {
    float f = c[j];
    s = fmaf(f, f, s);
    unsigned short h = f2bf_rne(f);
    float lo = f - bf2f(h);
    row[j] = h;
    row[64 + j] = f2bf_rne(lo);
  }
  cnorm[k] = s;
  hcn[k] = -0.5f * s;
}

// Each block: 256 rows. Each wave: 64 rows (4 row-tiles of 16).
// T = x.c - 0.5*|c|^2 ; dist = -2T + |x|^2  =>  argmin dist == argmax T.
__global__ __launch_bounds__(256) void vq_argmin_mfma_kernel(
    const float* __restrict__ x, const unsigned short* __restrict__ pk,
    const float* __restrict__ hcn, float* __restrict__ tok_out,
    unsigned int* __restrict__ counts, unsigned int* __restrict__ flag_cnt,
    unsigned int* __restrict__ flag_list) {
  __shared__ unsigned int hist[K];
  for (int i = threadIdx.x; i < K; i += 256) hist[i] = 0u;
  __syncthreads();

  const int lane = threadIdx.x & 63;
  const int w = threadIdx.x >> 6;
  const int c16 = lane & 15;  // A row within tile / B col within tile
  const int g4 = lane >> 4;   // k-group
  const int wave_base = blockIdx.x * 256 + w * 64;

  // A fragments: 4 row-tiles x 2 k-steps x (hi, lo), held for whole K loop
  short8v ah[4][2], al[4][2];
#pragma unroll
  for (int rt = 0; rt < 4; ++rt) {
#pragma unroll
    for (int s = 0; s < 2; ++s) {
      int row = wave_base + rt * 16 + c16;
      const float* p = x + (size_t)row * D + s * 32 + g4 * 8;
      float4 f0 = *(const float4*)(p);
      float4 f1 = *(const float4*)(p + 4);
      float ff[8] = {f0.x, f0.y, f0.z, f0.w, f1.x, f1.y, f1.z, f1.w};
      short8v h, l;
#pragma unroll
      for (int j = 0; j < 8; ++j) {
        unsigned short hb = f2bf_rne(ff[j]);
        float lo = ff[j] - bf2f(hb);
        h[j] = (short)hb;
        l[j] = (short)f2bf_rne(lo);
      }
      ah[rt][s] = h;
      al[rt][s] = l;
    }
  }

  float bT[4][4], b2T[4][4];
  int bidx[4][4];
#pragma unroll
  for (int rt = 0; rt < 4; ++rt)
#pragma unroll
    for (int r = 0; r < 4; ++r) {
      bT[rt][r] = -3.4e38f;
      b2T[rt][r] = -3.4e38f;
      bidx[rt][r] = 0;
    }

  const unsigned short* pbase = pk + (size_t)c16 * 128 + (size_t)g4 * 8;
  const float* hcnp = hcn + c16;

  for (int t = 0; t < K / 16; ++t) {
    short8v bh0 = *(const short8v*)(pbase);        // hi, k-step 0
    short8v bh1 = *(const short8v*)(pbase + 32);   // hi, k-step 1
    short8v bl0 = *(const short8v*)(pbase + 64);   // lo, k-step 0
    short8v bl1 = *(const short8v*)(pbase + 96);   // lo, k-step 1
    float hc = *hcnp;                              // -0.5*|c|^2 for this lane's col
    f32x4 cinit = {hc, hc, hc, hc};
    const int code = t * 16 + c16;
#pragma unroll
    for (int rt = 0; rt < 4; ++rt) {
      f32x4 acc = cinit;
      acc = __builtin_amdgcn_mfma_f32_16x16x32_bf16(ah[rt][0], bh0, acc, 0, 0, 0);
      acc = __builtin_amdgcn_mfma_f32_16x16x32_bf16(ah[rt][1], bh1, acc, 0, 0, 0);
      acc = __builtin_amdgcn_mfma_f32_16x16x32_bf16(ah[rt][0], bl0, acc, 0, 0, 0);
      acc = __builtin_amdgcn_mfma_f32_16x16x32_bf16(ah[rt][1], bl1, acc, 0, 0, 0);
      acc = __builtin_amdgcn_mfma_f32_16x16x32_bf16(al[rt][0], bh0, acc, 0, 0, 0);
      acc = __builtin_amdgcn_mfma_f32_16x16x32_bf16(al[rt][1], bh1, acc, 0, 0, 0);
#pragma unroll
      for (int r = 0; r < 4; ++r) {
        float T = acc[r];
        // second-max = max(old b2, min(old b, T))  (valid since b >= b2)
        b2T[rt][r] = fmaxf(b2T[rt][r], fminf(bT[rt][r], T));
        bool gt = T > bT[rt][r];  // strict > keeps earliest (lowest) code on tie
        bT[rt][r] = fmaxf(bT[rt][r], T);
        bidx[rt][r] = gt ? code : bidx[rt][r];
      }
    }
    pbase += 16 * 128;
    hcnp += 16;
  }

  // reduce across the 16 lanes (cols) of each lane-group; max T, lower idx on tie
#pragma unroll
  for (int rt = 0; rt < 4; ++rt) {
#pragma unroll
    for (int r = 0; r < 4; ++r) {
      float b = bT[rt][r], b2 = b2T[rt][r];
      int idx = bidx[rt][r];
#pragma unroll
      for (int m = 1; m < 16; m <<= 1) {
        float ob = __shfl_xor(b, m, 64);
        float ob2 = __shfl_xor(b2, m, 64);
        int oi = __shfl_xor(idx, m, 64);
        float nb2 = fmaxf(fmaxf(b2, ob2), fminf(b, ob));
        bool take = (ob > b) || (ob == b && oi < idx);
        b = take ? ob : b;
        idx = take ? oi : idx;
        b2 = nb2;
      }
      if (c16 == 0) {
        int grow = wave_base + rt * 16 + g4 * 4 + r;
        tok_out[grow] = (float)idx;
        atomicAdd(&hist[idx], 1u);
        // dist gap = 2*(b - b2); flag near-ties for exact fp32 recheck
        if (b - b2 < 0.5f * EPS_DIST) {
          unsigned p = atomicAdd(flag_cnt, 1u);
          if (p < FLAG_CAP) flag_list[p] = (unsigned)grow;
        }
      }
    }
  }
  __syncthreads();
  for (int i = threadIdx.x; i < K; i += 256) {
    unsigned h = hist[i];
    if (h) atomicAdd(&counts[i], h);
  }
}

// One wave per flagged vector: exact fp32 rescan, bit-identical formula to the
// round-1 kernel (which matched the numpy reference exactly).
// Lane l handles codes k = i*64 + l (i in 0..15): per-instruction footprint is
// 16 KB contiguous (256 B/lane stride) -> L1/L2 friendly.
__global__ __launch_bounds__(256) void vq_cleanup_kernel(
    const float* __restrict__ x, const float* __restrict__ cb,
    const float* __restrict__ cnorm, float* __restrict__ tok,
    unsigned int* __restrict__ counts, const unsigned int* __restrict__ flag_cnt,
    const unsigned int* __restrict__ flag_list) {
  const int lane = threadIdx.x & 63;
  const int gw = blockIdx.x * (blockDim.x >> 6) + (threadIdx.x >> 6);
  const int nw = gridDim.x * (blockDim.x >> 6);
  unsigned nf = *flag_cnt;
  if (nf > FLAG_CAP) nf = FLAG_CAP;
  for (unsigned f = gw; f < nf; f += nw) {
    int vid = (int)flag_list[f];
    const float* xv = x + (size_t)vid * D;
    float xr[D];
#pragma unroll
    for (int j = 0; j < 16; ++j) {
      float4 v = ((const float4*)xv)[j];
      xr[4 * j] = v.x; xr[4 * j + 1] = v.y;
      xr[4 * j + 2] = v.z; xr[4 * j + 3] = v.w;
    }
    float xx = 0.f;
#pragma unroll
    for (int j = 0; j < D; ++j) xx = fmaf(xr[j], xr[j], xx);
    float best = 3.4e38f;
    int bidx = K;
    for (int i = 0; i < 16; ++i) {
      int k = i * 64 + lane;  // ascending per lane -> strict < keeps lowest k
      const float* c = cb + (size_t)k * D;
      float acc = 0.f;
#pragma unroll
      for (int j = 0; j < D; ++j) acc = fmaf(xr[j], c[j], acc);
      float dist = (xx + cnorm[k]) - 2.0f * acc;
      if (dist < best) { best = dist; bidx = k; }
    }
#pragma unroll
    for (int m = 1; m < 64; m <<= 1) {
      float ob = __shfl_xor(best, m, 64);
      int oi = __shfl_xor(bidx, m, 64);
      bool take = (ob < best) || (ob == best && oi < bidx);
      best = take ? ob : best;
      bidx = take ? oi : bidx;
    }
    if (lane == 0) {
      int old = (int)tok[vid];
      if (old != bidx) {
        tok[vid] = (float)bidx;
        atomicAdd(&counts[old], 0xFFFFFFFFu);  // -1
        atomicAdd(&counts[bidx], 1u);
      }
    }
  }
}

__device__ __forceinline__ float block_reduce_sum_256(float v) {
#pragma unroll
  for (int o = 32; o > 0; o >>= 1) v += __shfl_down(v, o, 64);
  __shared__ float s[4];
  int lane = threadIdx.x & 63;
  int w = threadIdx.x >> 6;
  if (lane == 0) s[w] = v;
  __syncthreads();
  float r = 0.f;
  if (threadIdx.x == 0) r = s[0] + s[1] + s[2] + s[3];
  return r;  // valid on thread 0 only
}

__global__ __launch_bounds__(256) void vq_gather_kernel(
    const float* __restrict__ x, const float* __restrict__ cb,
    const float* __restrict__ tok, float* __restrict__ outq,
    float* __restrict__ sq_accum) {
  const int total4 = N_VEC * (D / 4);
  float sq = 0.f;
  for (int idx4 = blockIdx.x * 256 + threadIdx.x; idx4 < total4;
       idx4 += gridDim.x * 256) {
    int vid = idx4 >> 4;
    int j4 = idx4 & 15;
    int t = (int)tok[vid];
    float4 xv = reinterpret_cast<const float4*>(x)[idx4];
    float4 cv = reinterpret_cast<const float4*>(cb + (size_t)t * D)[j4];
    float dx0 = cv.x - xv.x, dx1 = cv.y - xv.y;
    float dx2 = cv.z - xv.z, dx3 = cv.w - xv.w;
    float4 q;
    q.x = xv.x + dx0; q.y = xv.y + dx1;
    q.z = xv.z + dx2; q.w = xv.w + dx3;
    reinterpret_cast<float4*>(outq)[idx4] = q;
    sq = fmaf(dx0, dx0, sq);
    sq = fmaf(dx1, dx1, sq);
    sq = fmaf(dx2, dx2, sq);
    sq = fmaf(dx3, dx3, sq);
  }
  float bs = block_reduce_sum_256(sq);
  if (threadIdx.x == 0) atomicAdd(sq_accum, bs);
}

__global__ __launch_bounds__(256) void vq_finalize_kernel(
    const unsigned int* __restrict__ counts, const float* __restrict__ sq_accum,
    float* __restrict__ out_scalars) {
  float h = 0.f;
  for (int i = threadIdx.x; i < K; i += 256) {
    float p = (float)counts[i] / (float)N_VEC;
    h -= p * logf(p + 1e-10f);
  }
  float hs = block_reduce_sum_256(h);
  if (threadIdx.x == 0) {
    float m = sq_accum[0] / (float)((size_t)N_VEC * D);
    out_scalars[0] = 1.25f * m;  // vq_loss
    out_scalars[1] = 0.25f * m;  // commitment_loss
    out_scalars[2] = m;          // codebook_loss
    out_scalars[3] = expf(hs);   // perplexity
  }
}

extern "C" void kernel_launch(void* const* d_in, const int* in_sizes, int n_in,
                              void* d_out, int out_size, void* d_ws,
                              size_t ws_size, hipStream_t stream) {
  const float* x = (const float*)d_in[0];
  const float* cb = (const float*)d_in[1];

  float* outq = (float*)d_out;
  float* tok = outq + (size_t)N_VEC * D;
  float* scal = tok + N_VEC;

  unsigned int* counts = (unsigned int*)d_ws;                 // K
  float* sq = (float*)d_ws + K;                               // 1
  unsigned int* flag_cnt = (unsigned int*)d_ws + K + 1;       // 1
  float* cnorm = (float*)d_ws + K + 4;                        // K
  float* hcn = (float*)d_ws + 2 * K + 4;                      // K
  unsigned int* flag_list = (unsigned int*)d_ws + 3 * K + 4;  // FLAG_CAP
  unsigned short* pk =
      (unsigned short*)((unsigned int*)d_ws + 3 * K + 4 + FLAG_CAP);

  // zero counts + sq + flag counter every call
  hipMemsetAsync(d_ws, 0, (size_t)(K + 2) * sizeof(float), stream);

  vq_prep_kernel<<<(K + 255) / 256, 256, 0, stream>>>(cb, cnorm, hcn, pk);
  vq_argmin_mfma_kernel<<<N_VEC / 256, 256, 0, stream>>>(
      x, pk, hcn, tok, counts, flag_cnt, flag_list);
  vq_cleanup_kernel<<<1024, 256, 0, stream>>>(x, cb, cnorm, tok, counts,
                                              flag_cnt, flag_list);
  vq_gather_kernel<<<4096, 256, 0, stream>>>(x, cb, tok, outq, sq);
  vq_finalize_kernel<<<1, 256, 0, stream>>>(counts, sq, scal);
}